// Round 1
// baseline (1882.874 us; speedup 1.0000x reference)
//
#include <hip/hip_runtime.h>
#include <math.h>

// ---------------------------------------------------------------------------
// ResidualLoss: res_l2 = ||b - A x|| / (||b|| + 1e-12), A in COO (NNZ=32M, N=1M)
// Pass 1: scatter-atomic SpMV into Ax (float, workspace)
// Pass 2: fused residual/target norm reduction (double accumulators)
// Pass 3: finalize scalar
// ---------------------------------------------------------------------------

__global__ __launch_bounds__(256) void spmv_scatter(
    const int* __restrict__ rows, const int* __restrict__ cols,
    const float* __restrict__ vals, const float* __restrict__ preds,
    float* __restrict__ Ax, int nnz4)
{
    int tid = blockIdx.x * blockDim.x + threadIdx.x;
    int stride = gridDim.x * blockDim.x;
    for (int i = tid; i < nnz4; i += stride) {
        int4   r = ((const int4*)rows)[i];
        int4   c = ((const int4*)cols)[i];
        float4 v = ((const float4*)vals)[i];
        atomicAdd(&Ax[r.x], v.x * preds[c.x]);
        atomicAdd(&Ax[r.y], v.y * preds[c.y]);
        atomicAdd(&Ax[r.z], v.z * preds[c.z]);
        atomicAdd(&Ax[r.w], v.w * preds[c.w]);
    }
}

__global__ __launch_bounds__(256) void residual_reduce(
    const float* __restrict__ Ax, const float* __restrict__ tb,
    double* __restrict__ acc, int n)
{
    float sr = 0.f, st = 0.f;
    int tid = blockIdx.x * blockDim.x + threadIdx.x;
    int stride = gridDim.x * blockDim.x;
    for (int i = tid; i < n; i += stride) {
        float t = tb[i];
        float r = t - Ax[i];
        sr += r * r;
        st += t * t;
    }
    // wave-64 reduce
    for (int off = 32; off > 0; off >>= 1) {
        sr += __shfl_down(sr, off);
        st += __shfl_down(st, off);
    }
    if ((threadIdx.x & 63) == 0) {
        atomicAdd(&acc[0], (double)sr);
        atomicAdd(&acc[1], (double)st);
    }
}

__global__ void finalize(const double* __restrict__ acc, float* __restrict__ out)
{
    if (threadIdx.x == 0 && blockIdx.x == 0) {
        double res = sqrt(acc[0]);
        double tgt = sqrt(acc[1]);
        out[0] = (float)(res / (tgt + 1e-12));
    }
}

extern "C" void kernel_launch(void* const* d_in, const int* in_sizes, int n_in,
                              void* d_out, int out_size, void* d_ws, size_t ws_size,
                              hipStream_t stream)
{
    const float* preds = (const float*)d_in[0];
    const float* tb    = (const float*)d_in[1];
    const int*   rows  = (const int*)d_in[2];
    const int*   cols  = (const int*)d_in[3];
    const float* vals  = (const float*)d_in[4];
    // d_in[5] = batch_map (unused)

    int n   = in_sizes[0];   // 1,000,000
    int nnz = in_sizes[2];   // 32,000,000

    double* acc = (double*)d_ws;                       // 2 doubles
    float*  Ax  = (float*)((char*)d_ws + 256);         // N floats

    // d_ws is re-poisoned to 0xAA before every timed call: must zero each time.
    hipMemsetAsync(d_ws, 0, 256 + (size_t)n * sizeof(float), stream);

    int nnz4 = nnz / 4;  // 32M divisible by 4
    spmv_scatter<<<2048, 256, 0, stream>>>(rows, cols, vals, preds, Ax, nnz4);
    residual_reduce<<<1024, 256, 0, stream>>>(Ax, tb, acc, n);
    finalize<<<1, 64, 0, stream>>>(acc, (float*)d_out);
}

// Round 2
// 1879.167 us; speedup vs baseline: 1.0020x; 1.0020x over previous
//
#include <hip/hip_runtime.h>
#include <math.h>

// ---------------------------------------------------------------------------
// ResidualLoss: res_l2 = ||b - A x|| / (||b|| + 1e-12), COO NNZ=32M, N=1M.
//
// Round-1 lesson: 32M device-scope float atomics = 1 GB of 32B write-through
// transactions at ~20.6 G/s -> 1553 us. Replace with counting-sort binning:
//   H  : per-chunk bucket histogram (bucket = row>>10, 1024 buckets/chunks)
//   P1 : per-bucket exclusive scan over chunks -> bases, totals
//   P2 : exclusive scan of totals -> starts
//   S  : stream COO once, scatter (row&1023, val*preds[col]) 8B pairs into
//        exactly-packed bucket regions (LDS cursors, no global atomics)
//   R  : per-bucket LDS accumulate + fused residual/target norms
//   F  : finalize scalar
// Falls back to the round-1 atomic path if ws_size < ~277 MB.
// ---------------------------------------------------------------------------

#define NBUK   1024
#define NCHUNK 1024
#define QPB    8192          // int4-quads per chunk; 1024*8192*4 = 32M entries

// ---- workspace layout (fast path) ----
// 0      : double acc[2]
// 1024   : int starts[1025]
// 8192   : int totals[1024]
// 16384  : int hist [NCHUNK][NBUK]   (4 MB)
// +4MB   : int bases[NCHUNK][NBUK]   (4 MB)
// +8MB   : uint2 pairs[32M]          (256 MB)
#define OFF_STARTS 1024
#define OFF_TOTALS 8192
#define OFF_HIST   16384
#define OFF_BASES  (16384 + (4u << 20))
#define OFF_PAIRS  (16384 + (8u << 20))

__global__ __launch_bounds__(256) void hist_kernel(
    const int* __restrict__ rows, int* __restrict__ hist)
{
    __shared__ int h[NBUK];
    for (int i = threadIdx.x; i < NBUK; i += 256) h[i] = 0;
    __syncthreads();
    int base = blockIdx.x * QPB;
    #pragma unroll 4
    for (int k = 0; k < QPB / 256; ++k) {
        int qi = base + k * 256 + threadIdx.x;
        int4 r = ((const int4*)rows)[qi];
        atomicAdd(&h[r.x >> 10], 1);
        atomicAdd(&h[r.y >> 10], 1);
        atomicAdd(&h[r.z >> 10], 1);
        atomicAdd(&h[r.w >> 10], 1);
    }
    __syncthreads();
    for (int i = threadIdx.x; i < NBUK; i += 256)
        hist[blockIdx.x * NBUK + i] = h[i];
}

// one block per bucket: exclusive scan over the 1024 chunk counts
__global__ __launch_bounds__(256) void colscan_kernel(
    const int* __restrict__ hist, int* __restrict__ bases,
    int* __restrict__ totals)
{
    int b = blockIdx.x;
    int t = threadIdx.x;
    int v[4]; int s = 0;
    #pragma unroll
    for (int j = 0; j < 4; ++j) { v[j] = hist[(t * 4 + j) * NBUK + b]; s += v[j]; }
    __shared__ int sc[256];
    sc[t] = s; __syncthreads();
    for (int off = 1; off < 256; off <<= 1) {
        int x = (t >= off) ? sc[t - off] : 0;
        __syncthreads();
        sc[t] += x;
        __syncthreads();
    }
    int excl = (t == 0) ? 0 : sc[t - 1];
    #pragma unroll
    for (int j = 0; j < 4; ++j) { bases[(t * 4 + j) * NBUK + b] = excl; excl += v[j]; }
    if (t == 255) totals[b] = sc[255];
}

__global__ __launch_bounds__(256) void scan_totals_kernel(
    const int* __restrict__ totals, int* __restrict__ starts)
{
    int t = threadIdx.x;
    int v[4]; int s = 0;
    #pragma unroll
    for (int j = 0; j < 4; ++j) { v[j] = totals[t * 4 + j]; s += v[j]; }
    __shared__ int sc[256];
    sc[t] = s; __syncthreads();
    for (int off = 1; off < 256; off <<= 1) {
        int x = (t >= off) ? sc[t - off] : 0;
        __syncthreads();
        sc[t] += x;
        __syncthreads();
    }
    int excl = (t == 0) ? 0 : sc[t - 1];
    #pragma unroll
    for (int j = 0; j < 4; ++j) { starts[t * 4 + j] = excl; excl += v[j]; }
    if (t == 255) starts[1024] = sc[255];
}

__global__ __launch_bounds__(256) void scatter_kernel(
    const int* __restrict__ rows, const int* __restrict__ cols,
    const float* __restrict__ vals, const float* __restrict__ preds,
    const int* __restrict__ starts, const int* __restrict__ bases,
    uint2* __restrict__ pairs)
{
    __shared__ int off[NBUK];
    int c = blockIdx.x;
    for (int i = threadIdx.x; i < NBUK; i += 256)
        off[i] = starts[i] + bases[c * NBUK + i];
    __syncthreads();
    int base = c * QPB;
    for (int k = 0; k < QPB / 256; ++k) {
        int qi = base + k * 256 + threadIdx.x;
        int4   r  = ((const int4*)rows)[qi];
        int4   cc = ((const int4*)cols)[qi];
        float4 v  = ((const float4*)vals)[qi];
        float p0 = v.x * preds[cc.x];
        float p1 = v.y * preds[cc.y];
        float p2 = v.z * preds[cc.z];
        float p3 = v.w * preds[cc.w];
        int s0 = atomicAdd(&off[r.x >> 10], 1);
        int s1 = atomicAdd(&off[r.y >> 10], 1);
        int s2 = atomicAdd(&off[r.z >> 10], 1);
        int s3 = atomicAdd(&off[r.w >> 10], 1);
        uint2 e;
        e.x = (unsigned)(r.x & 1023); e.y = __float_as_uint(p0); pairs[s0] = e;
        e.x = (unsigned)(r.y & 1023); e.y = __float_as_uint(p1); pairs[s1] = e;
        e.x = (unsigned)(r.z & 1023); e.y = __float_as_uint(p2); pairs[s2] = e;
        e.x = (unsigned)(r.w & 1023); e.y = __float_as_uint(p3); pairs[s3] = e;
    }
}

__global__ __launch_bounds__(256) void reduce_kernel(
    const uint2* __restrict__ pairs, const int* __restrict__ starts,
    const float* __restrict__ tb, double* __restrict__ acc, int n)
{
    __shared__ float a[NBUK];
    for (int i = threadIdx.x; i < NBUK; i += 256) a[i] = 0.f;
    __syncthreads();
    int b = blockIdx.x;
    int s0 = starts[b], s1 = starts[b + 1];
    for (int i = s0 + threadIdx.x; i < s1; i += 256) {
        uint2 e = pairs[i];
        atomicAdd(&a[e.x], __uint_as_float(e.y));
    }
    __syncthreads();
    float sr = 0.f, st = 0.f;
    int rbase = b << 10;
    for (int j = threadIdx.x; j < NBUK; j += 256) {
        int rowi = rbase + j;
        if (rowi < n) {
            float t = tb[rowi];
            float r = t - a[j];
            sr += r * r;
            st += t * t;
        }
    }
    #pragma unroll
    for (int o = 32; o > 0; o >>= 1) {
        sr += __shfl_down(sr, o);
        st += __shfl_down(st, o);
    }
    __shared__ double bsr[4], bst[4];
    int w = threadIdx.x >> 6;
    if ((threadIdx.x & 63) == 0) { bsr[w] = (double)sr; bst[w] = (double)st; }
    __syncthreads();
    if (threadIdx.x == 0) {
        double SR = bsr[0] + bsr[1] + bsr[2] + bsr[3];
        double ST = bst[0] + bst[1] + bst[2] + bst[3];
        atomicAdd(&acc[0], SR);
        atomicAdd(&acc[1], ST);
    }
}

__global__ void finalize(const double* __restrict__ acc, float* __restrict__ out)
{
    if (threadIdx.x == 0 && blockIdx.x == 0) {
        double res = sqrt(acc[0]);
        double tgt = sqrt(acc[1]);
        out[0] = (float)(res / (tgt + 1e-12));
    }
}

// ------------------------- fallback (round-1) path -------------------------
__global__ __launch_bounds__(256) void spmv_scatter(
    const int* __restrict__ rows, const int* __restrict__ cols,
    const float* __restrict__ vals, const float* __restrict__ preds,
    float* __restrict__ Ax, int nnz4)
{
    int tid = blockIdx.x * blockDim.x + threadIdx.x;
    int stride = gridDim.x * blockDim.x;
    for (int i = tid; i < nnz4; i += stride) {
        int4   r = ((const int4*)rows)[i];
        int4   c = ((const int4*)cols)[i];
        float4 v = ((const float4*)vals)[i];
        atomicAdd(&Ax[r.x], v.x * preds[c.x]);
        atomicAdd(&Ax[r.y], v.y * preds[c.y]);
        atomicAdd(&Ax[r.z], v.z * preds[c.z]);
        atomicAdd(&Ax[r.w], v.w * preds[c.w]);
    }
}

__global__ __launch_bounds__(256) void residual_reduce(
    const float* __restrict__ Ax, const float* __restrict__ tb,
    double* __restrict__ acc, int n)
{
    float sr = 0.f, st = 0.f;
    int tid = blockIdx.x * blockDim.x + threadIdx.x;
    int stride = gridDim.x * blockDim.x;
    for (int i = tid; i < n; i += stride) {
        float t = tb[i];
        float r = t - Ax[i];
        sr += r * r;
        st += t * t;
    }
    for (int off = 32; off > 0; off >>= 1) {
        sr += __shfl_down(sr, off);
        st += __shfl_down(st, off);
    }
    if ((threadIdx.x & 63) == 0) {
        atomicAdd(&acc[0], (double)sr);
        atomicAdd(&acc[1], (double)st);
    }
}

// ---------------------------------------------------------------------------
extern "C" void kernel_launch(void* const* d_in, const int* in_sizes, int n_in,
                              void* d_out, int out_size, void* d_ws, size_t ws_size,
                              hipStream_t stream)
{
    const float* preds = (const float*)d_in[0];
    const float* tb    = (const float*)d_in[1];
    const int*   rows  = (const int*)d_in[2];
    const int*   cols  = (const int*)d_in[3];
    const float* vals  = (const float*)d_in[4];

    int n   = in_sizes[0];   // 1,000,000
    int nnz = in_sizes[2];   // 32,000,000

    const size_t need = (size_t)OFF_PAIRS + (size_t)nnz * 8;
    const bool shape_ok = (nnz == NCHUNK * QPB * 4) && (n <= NBUK * 1024);

    double* acc = (double*)d_ws;

    if (shape_ok && ws_size >= need) {
        int*   starts = (int*)((char*)d_ws + OFF_STARTS);
        int*   totals = (int*)((char*)d_ws + OFF_TOTALS);
        int*   hist   = (int*)((char*)d_ws + OFF_HIST);
        int*   bases  = (int*)((char*)d_ws + OFF_BASES);
        uint2* pairs  = (uint2*)((char*)d_ws + OFF_PAIRS);

        hipMemsetAsync(d_ws, 0, 256, stream);  // acc[2]

        hist_kernel<<<NCHUNK, 256, 0, stream>>>(rows, hist);
        colscan_kernel<<<NBUK, 256, 0, stream>>>(hist, bases, totals);
        scan_totals_kernel<<<1, 256, 0, stream>>>(totals, starts);
        scatter_kernel<<<NCHUNK, 256, 0, stream>>>(rows, cols, vals, preds,
                                                   starts, bases, pairs);
        reduce_kernel<<<NBUK, 256, 0, stream>>>(pairs, starts, tb, acc, n);
        finalize<<<1, 64, 0, stream>>>(acc, (float*)d_out);
    } else {
        // round-1 atomic fallback
        float* Ax = (float*)((char*)d_ws + 256);
        hipMemsetAsync(d_ws, 0, 256 + (size_t)n * sizeof(float), stream);
        spmv_scatter<<<2048, 256, 0, stream>>>(rows, cols, vals, preds, Ax, nnz / 4);
        residual_reduce<<<1024, 256, 0, stream>>>(Ax, tb, acc, n);
        finalize<<<1, 64, 0, stream>>>(acc, (float*)d_out);
    }
}

// Round 8
// 1342.587 us; speedup vs baseline: 1.4024x; 1.3997x over previous
//
#include <hip/hip_runtime.h>
#include <math.h>

// ---------------------------------------------------------------------------
// ResidualLoss: res_l2 = ||b - A x|| / (||b|| + 1e-12), COO NNZ=32M, N=1M.
//
// R1 lesson: 32M device-scope float atomics = ~20.6 G atomics/s wall (1553us).
// R2 lesson: shape check nnz==1024*8192*4 (33.5M) != 32M -> fast path never ran.
// R3-R7: GPU acquisition timeouts — resubmitting untested counting-sort path.
//
// Counting-sort binning, runtime geometry, npass-adaptive workspace:
//  per pass over a slice of chunks:
//   H  : per-chunk bucket histogram (bucket = row>>10, 1024 buckets)
//   P1 : per-bucket scan over this pass's chunks -> bases, totals
//   P2 : scan totals -> starts
//   S  : stream COO slice, scatter (row&1023, val*preds[col]) 8B pairs into
//        exactly-packed bucket regions (LDS cursors; no global atomics)
//   R  : per-bucket LDS accumulate -> Ax (plain RMW, one block per bucket)
//  then: fused residual/target norm over Ax, finalize.
// ---------------------------------------------------------------------------

#define NBUK 1024

// ---- workspace layout ----
// 0      : double acc[2]
// 1024   : int starts[1025]
// 8192   : int totals[1024]
// 16384  : float Ax[n]            (<= 4 MB)
// then   : int hist [cpp][NBUK]
// then   : int bases[cpp][NBUK]
// then   : uint2 pairs[cpp*qpb*4]
#define OFF_STARTS 1024
#define OFF_TOTALS 8192
#define OFF_AX     16384

__global__ __launch_bounds__(256) void hist_kernel(
    const int* __restrict__ rows, int* __restrict__ hist,
    int quads, int qpb, int chunk0)
{
    __shared__ int h[NBUK];
    for (int i = threadIdx.x; i < NBUK; i += 256) h[i] = 0;
    __syncthreads();
    long long base = (long long)(chunk0 + blockIdx.x) * qpb;
    for (int idx = threadIdx.x; idx < qpb; idx += 256) {
        long long qi = base + idx;
        if (qi < quads) {
            int4 r = ((const int4*)rows)[qi];
            atomicAdd(&h[r.x >> 10], 1);
            atomicAdd(&h[r.y >> 10], 1);
            atomicAdd(&h[r.z >> 10], 1);
            atomicAdd(&h[r.w >> 10], 1);
        }
    }
    __syncthreads();
    for (int i = threadIdx.x; i < NBUK; i += 256)
        hist[blockIdx.x * NBUK + i] = h[i];
}

// one block per bucket: exclusive scan over this pass's cp chunk counts
__global__ __launch_bounds__(256) void colscan_kernel(
    const int* __restrict__ hist, int* __restrict__ bases,
    int* __restrict__ totals, int cp)
{
    int b = blockIdx.x, t = threadIdx.x;
    int v[4]; int s = 0;
    #pragma unroll
    for (int j = 0; j < 4; ++j) {
        int ch = t * 4 + j;
        v[j] = (ch < cp) ? hist[ch * NBUK + b] : 0;
        s += v[j];
    }
    __shared__ int sc[256];
    sc[t] = s; __syncthreads();
    for (int off = 1; off < 256; off <<= 1) {
        int x = (t >= off) ? sc[t - off] : 0;
        __syncthreads();
        sc[t] += x;
        __syncthreads();
    }
    int excl = (t == 0) ? 0 : sc[t - 1];
    #pragma unroll
    for (int j = 0; j < 4; ++j) {
        int ch = t * 4 + j;
        if (ch < cp) bases[ch * NBUK + b] = excl;
        excl += v[j];
    }
    if (t == 255) totals[b] = sc[255];
}

__global__ __launch_bounds__(256) void scan_totals_kernel(
    const int* __restrict__ totals, int* __restrict__ starts)
{
    int t = threadIdx.x;
    int v[4]; int s = 0;
    #pragma unroll
    for (int j = 0; j < 4; ++j) { v[j] = totals[t * 4 + j]; s += v[j]; }
    __shared__ int sc[256];
    sc[t] = s; __syncthreads();
    for (int off = 1; off < 256; off <<= 1) {
        int x = (t >= off) ? sc[t - off] : 0;
        __syncthreads();
        sc[t] += x;
        __syncthreads();
    }
    int excl = (t == 0) ? 0 : sc[t - 1];
    #pragma unroll
    for (int j = 0; j < 4; ++j) { starts[t * 4 + j] = excl; excl += v[j]; }
    if (t == 255) starts[1024] = sc[255];
}

__global__ __launch_bounds__(256) void scatter_kernel(
    const int* __restrict__ rows, const int* __restrict__ cols,
    const float* __restrict__ vals, const float* __restrict__ preds,
    const int* __restrict__ starts, const int* __restrict__ bases,
    uint2* __restrict__ pairs, int quads, int qpb, int chunk0)
{
    __shared__ int off[NBUK];
    int c = blockIdx.x;
    for (int i = threadIdx.x; i < NBUK; i += 256)
        off[i] = starts[i] + bases[c * NBUK + i];
    __syncthreads();
    long long base = (long long)(chunk0 + c) * qpb;
    for (int idx = threadIdx.x; idx < qpb; idx += 256) {
        long long qi = base + idx;
        if (qi < quads) {
            int4   r  = ((const int4*)rows)[qi];
            int4   cc = ((const int4*)cols)[qi];
            float4 v  = ((const float4*)vals)[qi];
            float p0 = v.x * preds[cc.x];
            float p1 = v.y * preds[cc.y];
            float p2 = v.z * preds[cc.z];
            float p3 = v.w * preds[cc.w];
            int s0 = atomicAdd(&off[r.x >> 10], 1);
            int s1 = atomicAdd(&off[r.y >> 10], 1);
            int s2 = atomicAdd(&off[r.z >> 10], 1);
            int s3 = atomicAdd(&off[r.w >> 10], 1);
            uint2 e;
            e.x = (unsigned)(r.x & 1023); e.y = __float_as_uint(p0); pairs[s0] = e;
            e.x = (unsigned)(r.y & 1023); e.y = __float_as_uint(p1); pairs[s1] = e;
            e.x = (unsigned)(r.z & 1023); e.y = __float_as_uint(p2); pairs[s2] = e;
            e.x = (unsigned)(r.w & 1023); e.y = __float_as_uint(p3); pairs[s3] = e;
        }
    }
}

// one block per bucket: LDS accumulate this pass's pairs, add into Ax
__global__ __launch_bounds__(256) void reduce_accum_kernel(
    const uint2* __restrict__ pairs, const int* __restrict__ starts,
    float* __restrict__ Ax, int n)
{
    __shared__ float a[NBUK];
    for (int i = threadIdx.x; i < NBUK; i += 256) a[i] = 0.f;
    __syncthreads();
    int b = blockIdx.x;
    int s0 = starts[b], s1 = starts[b + 1];
    for (int i = s0 + threadIdx.x; i < s1; i += 256) {
        uint2 e = pairs[i];
        atomicAdd(&a[e.x], __uint_as_float(e.y));
    }
    __syncthreads();
    int rbase = b << 10;
    for (int j = threadIdx.x; j < NBUK; j += 256) {
        int rowi = rbase + j;
        if (rowi < n) Ax[rowi] += a[j];
    }
}

__global__ __launch_bounds__(256) void residual_reduce(
    const float* __restrict__ Ax, const float* __restrict__ tb,
    double* __restrict__ acc, int n)
{
    float sr = 0.f, st = 0.f;
    int tid = blockIdx.x * blockDim.x + threadIdx.x;
    int stride = gridDim.x * blockDim.x;
    for (int i = tid; i < n; i += stride) {
        float t = tb[i];
        float r = t - Ax[i];
        sr += r * r;
        st += t * t;
    }
    #pragma unroll
    for (int off = 32; off > 0; off >>= 1) {
        sr += __shfl_down(sr, off);
        st += __shfl_down(st, off);
    }
    if ((threadIdx.x & 63) == 0) {
        atomicAdd(&acc[0], (double)sr);
        atomicAdd(&acc[1], (double)st);
    }
}

__global__ void finalize(const double* __restrict__ acc, float* __restrict__ out)
{
    if (threadIdx.x == 0 && blockIdx.x == 0) {
        double res = sqrt(acc[0]);
        double tgt = sqrt(acc[1]);
        out[0] = (float)(res / (tgt + 1e-12));
    }
}

// ------------------------- fallback (round-1) path -------------------------
__global__ __launch_bounds__(256) void spmv_scatter(
    const int* __restrict__ rows, const int* __restrict__ cols,
    const float* __restrict__ vals, const float* __restrict__ preds,
    float* __restrict__ Ax, int nnz)
{
    int tid = blockIdx.x * blockDim.x + threadIdx.x;
    int stride = gridDim.x * blockDim.x;
    for (int i = tid; i < nnz; i += stride)
        atomicAdd(&Ax[rows[i]], vals[i] * preds[cols[i]]);
}

// ---------------------------------------------------------------------------
extern "C" void kernel_launch(void* const* d_in, const int* in_sizes, int n_in,
                              void* d_out, int out_size, void* d_ws, size_t ws_size,
                              hipStream_t stream)
{
    const float* preds = (const float*)d_in[0];
    const float* tb    = (const float*)d_in[1];
    const int*   rows  = (const int*)d_in[2];
    const int*   cols  = (const int*)d_in[3];
    const float* vals  = (const float*)d_in[4];

    int n   = in_sizes[0];   // 1,000,000
    int nnz = in_sizes[2];   // 32,000,000

    double* acc = (double*)d_ws;

    bool shape_ok = (nnz % 4 == 0) && (n <= NBUK * 1024);
    int quads = nnz / 4;

    // chunk geometry: qpb quads per chunk, at most 1024 chunks
    int qpb = 8192;
    if ((long long)qpb * 1024 < quads) qpb = (int)((quads + 1023) / 1024);
    qpb = (qpb + 255) & ~255;
    int nchunk = (quads + qpb - 1) / qpb;

    // pick minimal npass whose workspace fits
    int npass = 0, cpp = 0;
    size_t off_hist = 0, off_bases = 0, off_pairs = 0;
    if (shape_ok) {
        size_t off_ax_end = (size_t)OFF_AX + (size_t)n * 4;
        off_ax_end = (off_ax_end + 255) & ~(size_t)255;
        for (int p = 1; p <= 16; p <<= 1) {
            int c = (nchunk + p - 1) / p;
            size_t oh = off_ax_end;
            size_t ob = oh + (size_t)c * NBUK * 4;
            size_t op = (ob + (size_t)c * NBUK * 4 + 255) & ~(size_t)255;
            size_t need = op + (size_t)c * qpb * 4 * 8;
            if (need <= ws_size) {
                npass = p; cpp = c;
                off_hist = oh; off_bases = ob; off_pairs = op;
                break;
            }
        }
    }

    if (npass > 0) {
        int*   starts = (int*)((char*)d_ws + OFF_STARTS);
        int*   totals = (int*)((char*)d_ws + OFF_TOTALS);
        float* Ax     = (float*)((char*)d_ws + OFF_AX);
        int*   hist   = (int*)((char*)d_ws + off_hist);
        int*   bases  = (int*)((char*)d_ws + off_bases);
        uint2* pairs  = (uint2*)((char*)d_ws + off_pairs);

        // zero acc + starts/totals + Ax (d_ws re-poisoned before every call)
        hipMemsetAsync(d_ws, 0, (size_t)OFF_AX + (size_t)n * 4, stream);

        for (int p = 0; p < npass; ++p) {
            int c0 = p * cpp;
            int cp = nchunk - c0; if (cp > cpp) cp = cpp;
            if (cp <= 0) break;
            hist_kernel<<<cp, 256, 0, stream>>>(rows, hist, quads, qpb, c0);
            colscan_kernel<<<NBUK, 256, 0, stream>>>(hist, bases, totals, cp);
            scan_totals_kernel<<<1, 256, 0, stream>>>(totals, starts);
            scatter_kernel<<<cp, 256, 0, stream>>>(rows, cols, vals, preds,
                                                   starts, bases, pairs,
                                                   quads, qpb, c0);
            reduce_accum_kernel<<<NBUK, 256, 0, stream>>>(pairs, starts, Ax, n);
        }
        residual_reduce<<<1024, 256, 0, stream>>>(Ax, tb, acc, n);
        finalize<<<1, 64, 0, stream>>>(acc, (float*)d_out);
    } else {
        // atomic fallback
        float* Ax = (float*)((char*)d_ws + 256);
        hipMemsetAsync(d_ws, 0, 256 + (size_t)n * sizeof(float), stream);
        spmv_scatter<<<2048, 256, 0, stream>>>(rows, cols, vals, preds, Ax, nnz);
        residual_reduce<<<1024, 256, 0, stream>>>(Ax, tb, acc, n);
        finalize<<<1, 64, 0, stream>>>(acc, (float*)d_out);
    }
}